// Round 2
// baseline (174.337 us; speedup 1.0000x reference)
//
#include <hip/hip_runtime.h>
#include <math.h>

// Problem constants
#define B_   8
#define L_   256
#define C_   512
#define OUT_ 512

typedef _Float16 half8 __attribute__((ext_vector_type(8)));
typedef _Float16 half4 __attribute__((ext_vector_type(4)));
typedef float    f32x4 __attribute__((ext_vector_type(4)));
typedef float    f32x2 __attribute__((ext_vector_type(2)));

// ---------------------------------------------------------------------------
// Kernel 0 (NEW): one-shot conversions.
//  task 0/1: Xh = (half)relu(X) for xt/xd            (2048x512 each)
//  task 2/3: Wt[n][k] = (half)W[k][n] for Wp/Wc      (512x512 transpose+cvt)
// Moves ALL f32->f16 conversion out of the GEMM inner loops (was redundantly
// re-converted 8-32x per tile in old proj staging). grid (64,1,4), 256 thr.
// ---------------------------------------------------------------------------
__global__ __launch_bounds__(256)
void prep_kernel(const float* __restrict__ xt, const float* __restrict__ xd,
                 const float* __restrict__ Wp, const float* __restrict__ Wc,
                 _Float16* __restrict__ Xth, _Float16* __restrict__ Xdh,
                 _Float16* __restrict__ Wpt, _Float16* __restrict__ Wct)
{
    const int task = blockIdx.z;
    const int tid = threadIdx.x;
    if (task < 2) {
        const float* __restrict__ src = task ? xd : xt;
        _Float16*    __restrict__ dst = task ? Xdh : Xth;
        const size_t base = (size_t)blockIdx.x * 16384;
        #pragma unroll
        for (int it = 0; it < 16; ++it) {
            const size_t o = base + ((size_t)it * 256 + tid) * 4;
            const float4 v = *(const float4*)(src + o);
            half4 h;
            h[0] = (_Float16)fmaxf(v.x, 0.f);
            h[1] = (_Float16)fmaxf(v.y, 0.f);
            h[2] = (_Float16)fmaxf(v.z, 0.f);
            h[3] = (_Float16)fmaxf(v.w, 0.f);
            *(half4*)(dst + o) = h;
        }
    } else {
        const float* __restrict__ src = (task == 3) ? Wc : Wp;   // [k][n]
        _Float16*    __restrict__ dst = (task == 3) ? Wct : Wpt; // [n][k]
        __shared__ _Float16 tr[64][80];   // row stride 160B (16B-aligned half8)
        const int tx = (blockIdx.x & 7) << 6;    // k base
        const int ty = (blockIdx.x >> 3) << 6;   // n base
        const int r0 = tid >> 4;                 // 0..15
        const int c4 = (tid & 15) << 2;          // 0..60
        #pragma unroll
        for (int p = 0; p < 4; ++p) {
            const int kr = r0 + (p << 4);        // 0..63
            const float4 v = *(const float4*)(src + (size_t)(tx + kr) * C_ + ty + c4);
            tr[c4 + 0][kr] = (_Float16)v.x;
            tr[c4 + 1][kr] = (_Float16)v.y;
            tr[c4 + 2][kr] = (_Float16)v.z;
            tr[c4 + 3][kr] = (_Float16)v.w;
        }
        __syncthreads();
        const int nr = tid >> 3;                 // 0..31
        const int k8 = (tid & 7) << 3;           // 0..56
        #pragma unroll
        for (int p = 0; p < 2; ++p)
            *(half8*)(dst + (size_t)(ty + nr + (p << 5)) * C_ + tx + k8) =
                *(const half8*)&tr[nr + (p << 5)][k8];
    }
}

// ---------------------------------------------------------------------------
// Kernel 1 (REWRITE): projection GEMM, per-wave 16x16 tile, frags direct from
// global (L2-resident f16, layouts already fragment-shaped -> no LDS, no
// barriers, no cvt). 2 indep MFMA chains. grid (512,2) x 512 thr = 32 wv/CU.
//   Y[m][n] = sum_k Xh[m][k] * Wt[n][k] + bias[n]
// ---------------------------------------------------------------------------
__global__ __launch_bounds__(512)
void proj_mfma_kernel(const _Float16* __restrict__ Xth, const _Float16* __restrict__ Xdh,
                      const _Float16* __restrict__ Wpt, const _Float16* __restrict__ Wct,
                      const float* __restrict__ bp, const float* __restrict__ bc,
                      _Float16* __restrict__ pt, _Float16* __restrict__ pc)
{
    const int which = blockIdx.y;
    const _Float16* __restrict__ Xh = which ? Xdh : Xth;
    const _Float16* __restrict__ Wt = which ? Wct : Wpt;
    const float*    __restrict__ bias = which ? bc : bp;
    _Float16*       __restrict__ Y  = which ? pc : pt;

    const int tid = threadIdx.x;
    const int wv = tid >> 6, lane = tid & 63;
    const int l15 = lane & 15, quad = lane >> 4;
    const int id = ((int)blockIdx.x << 3) + wv;   // 0..4095
    const int m0 = (id >> 5) << 4;                // 0..2032
    const int n0 = (id & 31) << 4;                // 0..496

    const _Float16* __restrict__ Ap = Xh + (size_t)(m0 + l15) * C_ + (quad << 3);
    const _Float16* __restrict__ Bp = Wt + (size_t)(n0 + l15) * C_ + (quad << 3);

    f32x4 acc0 = {}, acc1 = {};
    #pragma unroll
    for (int ks = 0; ks < 8; ++ks) {
        half8 a0 = *(const half8*)(Ap + (ks << 5));
        half8 b0 = *(const half8*)(Bp + (ks << 5));
        acc0 = __builtin_amdgcn_mfma_f32_16x16x32_f16(a0, b0, acc0, 0, 0, 0);
        half8 a1 = *(const half8*)(Ap + ((ks + 8) << 5));
        half8 b1 = *(const half8*)(Bp + ((ks + 8) << 5));
        acc1 = __builtin_amdgcn_mfma_f32_16x16x32_f16(a1, b1, acc1, 0, 0, 0);
    }
    const f32x4 acc = acc0 + acc1;
    const float bz = bias[n0 + l15];
    // C/D: col = lane&15 (n), row = quad*4 + r (m)
    #pragma unroll
    for (int r = 0; r < 4; ++r)
        Y[(size_t)(m0 + (quad << 2) + r) * C_ + n0 + l15] = (_Float16)(acc[r] + bz);
}

// ---------------------------------------------------------------------------
__device__ __forceinline__ float sigmoid_fast(float z) {
    float e = __builtin_amdgcn_exp2f(-1.4426950408889634f * z);
    return __builtin_amdgcn_rcpf(e + 1.0f);
}

// ---------------------------------------------------------------------------
// Kernel 2a: sigmoid scores. Per-wave 16x16 (i,j) tile, frags direct from
// global, 2 indep MFMA chains. grid (2,16,8) x 512 thr. Writes w + block sums.
// ---------------------------------------------------------------------------
__global__ __launch_bounds__(512)
void scores_kernel(const _Float16* __restrict__ pt, const _Float16* __restrict__ pc,
                   float* __restrict__ w, float* __restrict__ sums_part)
{
    const int bx = blockIdx.x, by = blockIdx.y, b = blockIdx.z;
    const int tid = threadIdx.x;
    const int wv = tid >> 6, lane = tid & 63;
    const int l15 = lane & 15, quad = lane >> 4;
    const int i0 = ((bx << 3) + wv) << 4;   // i-tile = bx*8+wv
    const int j0 = by << 4;

    __shared__ float wred[8];

    const _Float16* __restrict__ Ap = pt + (size_t)(b * L_ + i0 + l15) * C_ + (quad << 3);
    const _Float16* __restrict__ Bp = pc + (size_t)(b * L_ + j0 + l15) * C_ + (quad << 3);

    f32x4 acc0 = {}, acc1 = {};
    #pragma unroll
    for (int ks = 0; ks < 8; ++ks) {
        half8 a0 = *(const half8*)(Ap + (ks << 5));
        half8 b0 = *(const half8*)(Bp + (ks << 5));
        acc0 = __builtin_amdgcn_mfma_f32_16x16x32_f16(a0, b0, acc0, 0, 0, 0);
        half8 a1 = *(const half8*)(Ap + ((ks + 8) << 5));
        half8 b1 = *(const half8*)(Bp + ((ks + 8) << 5));
        acc1 = __builtin_amdgcn_mfma_f32_16x16x32_f16(a1, b1, acc1, 0, 0, 0);
    }
    const f32x4 acc = acc0 + acc1;

    float4 sg;
    sg.x = sigmoid_fast(acc[0]);
    sg.y = sigmoid_fast(acc[1]);
    sg.z = sigmoid_fast(acc[2]);
    sg.w = sigmoid_fast(acc[3]);

    // C/D: col = lane&15 (j), row = quad*4 + r (i)
    float* __restrict__ wp = w + (size_t)(b * L_ + i0 + (quad << 2)) * L_ + j0 + l15;
    wp[0 * L_] = sg.x;
    wp[1 * L_] = sg.y;
    wp[2 * L_] = sg.z;
    wp[3 * L_] = sg.w;

    float lsum = (sg.x + sg.y) + (sg.z + sg.w);
    #pragma unroll
    for (int off = 32; off; off >>= 1) lsum += __shfl_xor(lsum, off);
    if (lane == 0) wred[wv] = lsum;
    __syncthreads();
    if (tid == 0) {
        float s = 0.f;
        #pragma unroll
        for (int v = 0; v < 8; ++v) s += wred[v];
        sums_part[(b << 5) | (by << 1) | bx] = s;
    }
}

// ---------------------------------------------------------------------------
// Kernel 2b (TUNE): weighted tanh-r accumulation.
//   partial[b][p][c] = sum_{i,j in 16x16 tile} w[i][j] * r(xd[i,c]*xt[j,c]),
//   r = 1/(1+exp2(2*log2e*x));  tanh = 1-2r recovered in finalize.
// v2: xt preloaded+prescaled in regs (16), distance-2 LDS w-quad prefetch,
// ws_ stride 24 (16B-aligned b128, broadcast reads). launch_bounds (512,6)
// for register headroom. grid (16,16,8) x 512 thr (thread = channel).
// ---------------------------------------------------------------------------
__global__ __launch_bounds__(512, 6)
void tanh_cp_kernel(const float* __restrict__ w, const float* __restrict__ xd,
                    const float* __restrict__ xt, float* __restrict__ partials)
{
    const int bx = blockIdx.x, by = blockIdx.y, b = blockIdx.z;
    const int i0 = bx << 4, j0 = by << 4;
    const int tid = threadIdx.x;

    __shared__ float ws_[16][24];     // [j][i], row stride 96B (16B-aligned)

    if (tid < 64) {
        const int ir = tid >> 2, j4 = (tid & 3) << 2;
        const float4 v = *(const float4*)(w + (size_t)(b * L_ + i0 + ir) * L_ + j0 + j4);
        ws_[j4 + 0][ir] = v.x;
        ws_[j4 + 1][ir] = v.y;
        ws_[j4 + 2][ir] = v.z;
        ws_[j4 + 3][ir] = v.w;
    }

    const int c = tid;
    const float* __restrict__ xdb = xd + (size_t)(b * L_ + i0) * C_ + c;
    const float* __restrict__ xtb = xt + (size_t)(b * L_ + j0) * C_ + c;

    float xtv[16];                    // prescaled by 2*log2(e)
    #pragma unroll
    for (int j = 0; j < 16; ++j)
        xtv[j] = xtb[(size_t)j * C_] * 2.8853900817779268f;

    f32x2 xds2[8];                    // 16 xd rows, packed in pairs
    #pragma unroll
    for (int i = 0; i < 8; ++i) {
        xds2[i].x = xdb[(size_t)(2 * i) * C_];
        xds2[i].y = xdb[(size_t)(2 * i + 1) * C_];
    }

    __syncthreads();

    f32x2 acc01 = {0.f, 0.f}, acc23 = {0.f, 0.f};
    // 64 quad-steps: q -> (jj = q>>2, iq = q&3); each consumes one float4 of w
    float4 wb0 = *(const float4*)&ws_[0][0];
    float4 wb1 = *(const float4*)&ws_[0][4];
    #pragma unroll
    for (int q = 0; q < 64; ++q) {
        float4 wn = wb1;
        if (q < 62) {
            const int qq = q + 2;
            wn = *(const float4*)&ws_[qq >> 2][(qq & 3) << 2];
        }
        const float xv = xtv[q >> 2];
        const int h = (q & 3) << 1;
        // pair (4q, 4q+1)
        f32x2 x01 = xds2[h] * xv;                                  // v_pk_mul
        f32x2 e01 = { __builtin_amdgcn_exp2f(x01.x), __builtin_amdgcn_exp2f(x01.y) };
        f32x2 q01 = e01 + 1.0f;                                    // v_pk_add
        float rp01 = __builtin_amdgcn_rcpf(q01.x * q01.y);
        f32x2 r01 = rp01 * __builtin_shufflevector(q01, q01, 1, 0);
        f32x2 w01 = { wb0.x, wb0.y };
        acc01 = w01 * r01 + acc01;                                 // v_pk_fma
        // pair (4q+2, 4q+3)
        f32x2 x23 = xds2[h + 1] * xv;
        f32x2 e23 = { __builtin_amdgcn_exp2f(x23.x), __builtin_amdgcn_exp2f(x23.y) };
        f32x2 q23 = e23 + 1.0f;
        float rp23 = __builtin_amdgcn_rcpf(q23.x * q23.y);
        f32x2 r23 = rp23 * __builtin_shufflevector(q23, q23, 1, 0);
        f32x2 w23 = { wb0.z, wb0.w };
        acc23 = w23 * r23 + acc23;
        wb0 = wb1; wb1 = wn;
    }
    const int p = (bx << 4) | by;     // 0..255
    partials[(size_t)((b << 8) | p) * C_ + c] =
        (acc01.x + acc01.y) + (acc23.x + acc23.y);
}

// ---------------------------------------------------------------------------
// Kernel 3: S = sum(scores); cp[b,c] = 1 - 2*(sum_p partial)/S; out = cp@Wf+bf
// grid (8,8), 512 thr. (32 sums/b, 256 partials/b)
// ---------------------------------------------------------------------------
__global__ __launch_bounds__(512)
void finalize_kernel(const float* __restrict__ partials, const float* __restrict__ sums_part,
                     const float* __restrict__ Wf, const float* __restrict__ bfv,
                     float* __restrict__ out)
{
    const int b = blockIdx.y;
    const int t = threadIdx.x;
    __shared__ float cp[C_];
    __shared__ float red[512];
    __shared__ float sumsh;

    red[t] = (t < 32) ? sums_part[(b << 5) | t] : 0.f;

    float s = 0.f;
    #pragma unroll 8
    for (int p = 0; p < 256; ++p)
        s += partials[(size_t)((b << 8) | p) * C_ + t];

    __syncthreads();
    for (int st = 256; st > 0; st >>= 1) {
        if (t < st) red[t] += red[t + st];
        __syncthreads();
    }
    if (t == 0) sumsh = red[0];
    __syncthreads();

    cp[t] = 1.0f - 2.0f * s / sumsh;
    __syncthreads();

    const int o  = ((int)blockIdx.x << 6) | (t & 63);
    const int c0 = (t >> 6) << 6;
    float acc = 0.f;
    #pragma unroll 8
    for (int i = 0; i < 64; ++i) {
        const int cc = c0 + i;
        acc = fmaf(cp[cc], Wf[(size_t)cc * OUT_ + o], acc);
    }
    red[t] = acc;
    __syncthreads();
    if (t < 64) {
        float a = 0.f;
        #pragma unroll
        for (int g = 0; g < 8; ++g) a += red[(g << 6) | t];
        out[(size_t)b * OUT_ + o] = a + bfv[o];
    }
}

// ---------------------------------------------------------------------------
extern "C" void kernel_launch(void* const* d_in, const int* in_sizes, int n_in,
                              void* d_out, int out_size, void* d_ws, size_t ws_size,
                              hipStream_t stream)
{
    const float* xd = (const float*)d_in[0];
    const float* xt = (const float*)d_in[1];
    const float* Wc = (const float*)d_in[2];
    const float* bc = (const float*)d_in[3];
    const float* Wp = (const float*)d_in[4];
    const float* bp = (const float*)d_in[5];
    const float* Wf = (const float*)d_in[6];
    const float* bf = (const float*)d_in[7];
    float* out = (float*)d_out;

    // workspace (~15 MB)
    _Float16* Xth = (_Float16*)d_ws;                 // 2048x512 f16 = 2 MB
    _Float16* Xdh = Xth + 1048576;                   // 2 MB
    _Float16* Wpt = Xdh + 1048576;                   // 512x512 f16 = 0.5 MB
    _Float16* Wct = Wpt + 262144;                    // 0.5 MB
    _Float16* pt  = Wct + 262144;                    // 2 MB
    _Float16* pc  = pt + 1048576;                    // 2 MB
    float* w         = (float*)(pc + 1048576);       // 8*256*256 f = 2 MB
    float* partials  = w + 524288;                   // 8*256*512 f = 4 MB
    float* sums_part = partials + 1048576;           // 256 f

    prep_kernel<<<dim3(64, 1, 4), 256, 0, stream>>>(xt, xd, Wp, Wc, Xth, Xdh, Wpt, Wct);
    proj_mfma_kernel<<<dim3(512, 2), 512, 0, stream>>>(Xth, Xdh, Wpt, Wct, bp, bc, pt, pc);
    scores_kernel<<<dim3(2, 16, 8), 512, 0, stream>>>(pt, pc, w, sums_part);
    tanh_cp_kernel<<<dim3(16, 16, 8), 512, 0, stream>>>(w, xd, xt, partials);
    finalize_kernel<<<dim3(8, 8), 512, 0, stream>>>(partials, sums_part, Wf, bf, out);
}